// Round 5
// baseline (297.879 us; speedup 1.0000x reference)
//
#include <hip/hip_runtime.h>
#include <math.h>

#define UNITS 80
#define LATENT 128
#define IN_DIM 256
#define BATCH 8192
#define SEQ 256
#define G 320           // 4*UNITS
#define H2 160          // 2*UNITS
#define ROW_F4 (SEQ * UNITS / 4)       // 5120 float4 per batch row
#define BODY_F4 ((SEQ - 1) * UNITS / 4) // 5100 float4 in the s>=1 region

#define TPB 640
#define RPB_C 16                        // rows per compute block
#define NCB (BATCH / RPB_C)             // 512 compute blocks (+1 yc block)
#define RPB_W 4                         // rows per writer block
#define NWB (BATCH / RPB_W)             // 2048 writer blocks

typedef float f4 __attribute__((ext_vector_type(4)));

__device__ __forceinline__ float sigf(float v) {
    return 1.0f / (1.0f + __expf(-v));
}

// ---------------------------------------------------------------------------
// K1: block 0 computes yc = decode_step(ones); blocks 1..512 compute y0 for 16
// rows each and nt-write the s=0 slices.
// ---------------------------------------------------------------------------
__global__ __launch_bounds__(TPB)
void compute_kernel(const float* __restrict__ x,
                    const float* __restrict__ Wl, const float* __restrict__ bl,
                    const float* __restrict__ Kf, const float* __restrict__ bf,
                    const float* __restrict__ Kb, const float* __restrict__ bb,
                    const float* __restrict__ Kw1, const float* __restrict__ b1,
                    float* __restrict__ yc, float* __restrict__ out) {
    __shared__ float xs[RPB_C * IN_DIM];     // 16 KB
    __shared__ float lat_s[RPB_C * LATENT];  // 8 KB
    __shared__ float h_s[RPB_C * H2];        // 10 KB
    __shared__ float z[2 * G];               // 2.56 KB (yc path)
    __shared__ float hh[H2];                 // 0.64 KB (yc path)

    const int t = threadIdx.x;
    const int bid = blockIdx.x;

    if (bid == 0) {
        // ----- yc path: input all-ones => z = colsum(K) + b -----
        {
            const float* K   = (t < G) ? Kf : Kb;
            const float* bia = (t < G) ? bf : bb;
            const int c = (t < G) ? t : t - G;
            float acc = bia[c];
#pragma unroll 8
            for (int l = 0; l < LATENT; ++l) acc += K[l * G + c];
            z[t] = acc;
        }
        __syncthreads();
        if (t < UNITS) {
            hh[t] = sigf(z[240 + t]) * sigf(z[t]) * fmaxf(z[160 + t], 0.f);
        } else if (t >= G && t < G + UNITS) {
            const int u = t - G;
            hh[UNITS + u] = sigf(z[G + 240 + u]) * sigf(z[G + u]) * fmaxf(z[G + 160 + u], 0.f);
        }
        __syncthreads();
        if (t < G) {
            float acc = b1[t];
#pragma unroll 8
            for (int l = 0; l < H2; ++l) acc = fmaf(hh[l], Kw1[l * G + t], acc);
            z[t] = acc;
        }
        __syncthreads();
        if (t < UNITS) yc[t] = sigf(z[240 + t]) * sigf(z[t]) * fmaxf(z[160 + t], 0.f);
        return;
    }

    // ----- y0 path: rows R0 .. R0+15 -----
    const int R0 = (bid - 1) * RPB_C;

    // stage x tile (16 rows x 256 f32 = 1024 f4)
    {
        const f4* xg = (const f4*)(x + (size_t)R0 * IN_DIM);
        f4* xs4 = (f4*)xs;
        for (int i = t; i < RPB_C * IN_DIM / 4; i += TPB) xs4[i] = xg[i];
    }
    __syncthreads();

    // lat = x @ W_lat + b_lat : 16*128 = 2048 outputs
    for (int i = t; i < RPB_C * LATENT; i += TPB) {
        const int row = i >> 7, col = i & 127;
        float acc = bl[col];
        const float* xr = xs + row * IN_DIM;
#pragma unroll 8
        for (int l = 0; l < IN_DIM; ++l) acc = fmaf(xr[l], Wl[l * LATENT + col], acc);
        lat_s[i] = acc;
    }
    __syncthreads();

    // fw/bw gates: 2*16*80 = 2560 outputs (f gate dead: c0=0; relu(c)=c, c>=0)
    for (int i = t; i < 2 * RPB_C * UNITS; i += TPB) {
        const int half = (i >= RPB_C * UNITS);
        const int j = half ? i - RPB_C * UNITS : i;
        const int row = j / UNITS;
        const int u = j - row * UNITS;
        const float* K   = half ? Kb : Kf;
        const float* bia = half ? bb : bf;
        float ai = 0.f, ac = 0.f, ao = 0.f;
        const float* lr = lat_s + row * LATENT;
#pragma unroll 4
        for (int k = 0; k < LATENT; ++k) {
            const float lv = lr[k];
            ai = fmaf(lv, K[k * G + u], ai);
            ac = fmaf(lv, K[k * G + 160 + u], ac);
            ao = fmaf(lv, K[k * G + 240 + u], ao);
        }
        h_s[row * H2 + half * UNITS + u] =
            sigf(ao + bia[240 + u]) * sigf(ai + bia[u]) * fmaxf(ac + bia[160 + u], 0.f);
    }
    __syncthreads();

    // output LSTM: 16*80 = 1280 outputs, nt-write s=0 slices
    for (int i = t; i < RPB_C * UNITS; i += TPB) {
        const int row = i / UNITS;
        const int u = i - row * UNITS;
        float ai = 0.f, ac = 0.f, ao = 0.f;
        const float* hr = h_s + row * H2;
#pragma unroll 4
        for (int k = 0; k < H2; ++k) {
            const float hv = hr[k];
            ai = fmaf(hv, Kw1[k * G + u], ai);
            ac = fmaf(hv, Kw1[k * G + 160 + u], ac);
            ao = fmaf(hv, Kw1[k * G + 240 + u], ao);
        }
        const float y = sigf(ao + b1[240 + u]) * sigf(ai + b1[u]) * fmaxf(ac + b1[160 + u], 0.f);
        __builtin_nontemporal_store(y, out + (size_t)(R0 + row) * SEQ * UNITS + u);
    }
}

// ---------------------------------------------------------------------------
// K2: pure writer. Each block broadcasts yc into the s>=1 region of 4 rows.
// No global reads in the hot loop; minimal VGPR; contiguous nt f4 stores.
// ---------------------------------------------------------------------------
__global__ __launch_bounds__(TPB)
void writer_kernel(const float* __restrict__ yc, float* __restrict__ out) {
    __shared__ f4 ycs[UNITS / 4];
    const int t = threadIdx.x;
    if (t < UNITS / 4) ycs[t] = ((const f4*)yc)[t];
    __syncthreads();
    const f4 yv = ycs[t % (UNITS / 4)];   // constant per thread (640 % 20 == 0)

    f4* rowp = (f4*)out + (size_t)blockIdx.x * RPB_W * ROW_F4 + (UNITS / 4);
#pragma unroll
    for (int r = 0; r < RPB_W; ++r) {
#pragma unroll
        for (int k = 0; k < 8; ++k) {
            const int j = t + k * TPB;
            if (j < BODY_F4) __builtin_nontemporal_store(yv, rowp + j);
        }
        rowp += ROW_F4;
    }
}

extern "C" void kernel_launch(void* const* d_in, const int* in_sizes, int n_in,
                              void* d_out, int out_size, void* d_ws, size_t ws_size,
                              hipStream_t stream) {
    const float* x   = (const float*)d_in[0];
    // d_in[1] = size (scalar, fixed 256)
    const float* Wl  = (const float*)d_in[2];
    const float* bl  = (const float*)d_in[3];
    const float* Kf  = (const float*)d_in[4];
    const float* bf  = (const float*)d_in[5];
    const float* Kb  = (const float*)d_in[6];
    const float* bb  = (const float*)d_in[7];
    const float* Kw1 = (const float*)d_in[8];
    const float* b1  = (const float*)d_in[9];
    float* out = (float*)d_out;
    float* yc  = (float*)d_ws;   // 80 floats

    compute_kernel<<<NCB + 1, TPB, 0, stream>>>(x, Wl, bl, Kf, bf, Kb, bb, Kw1, b1, yc, out);
    writer_kernel<<<NWB, TPB, 0, stream>>>(yc, out);
}

// Round 6
// 185.269 us; speedup vs baseline: 1.6078x; 1.6078x over previous
//
#include <hip/hip_runtime.h>
#include <math.h>

#define UNITS 80
#define LATENT 128
#define IN_DIM 256
#define BATCH 8192
#define SEQ 256
#define G 320           // 4*UNITS
#define H2 160          // 2*UNITS

#define TPB 640         // 10 waves; 640 % 20 == 0 (yc float4 period)
#define RPB 4           // batch rows per block
#define NBLK (BATCH / RPB)   // 2048 blocks

typedef float f4 __attribute__((ext_vector_type(4)));

__device__ __forceinline__ float sigf(float v) {
    return 1.0f / (1.0f + __expf(-v));
}

// ---------------------------------------------------------------------------
// Kernel 1: yc = decode_step(ones(128)). Input all-ones => z = colsum(K) + b.
// ---------------------------------------------------------------------------
__global__ __launch_bounds__(640)
void yc_kernel(const float* __restrict__ Kf, const float* __restrict__ bf,
               const float* __restrict__ Kb, const float* __restrict__ bb,
               const float* __restrict__ K1, const float* __restrict__ b1,
               float* __restrict__ yc) {
    __shared__ float z[2 * G];
    __shared__ float h[H2];
    const int t = threadIdx.x;   // 0..639

    {
        const float* K   = (t < G) ? Kf : Kb;
        const float* bia = (t < G) ? bf : bb;
        const int c = (t < G) ? t : t - G;
        float acc = bia[c];
#pragma unroll 8
        for (int l = 0; l < LATENT; ++l) acc += K[l * G + c];
        z[t] = acc;
    }
    __syncthreads();
    if (t < UNITS) {
        h[t] = sigf(z[240 + t]) * sigf(z[t]) * fmaxf(z[160 + t], 0.f);
    } else if (t >= G && t < G + UNITS) {
        const int u = t - G;
        h[UNITS + u] = sigf(z[G + 240 + u]) * sigf(z[G + u]) * fmaxf(z[G + 160 + u], 0.f);
    }
    __syncthreads();
    if (t < G) {
        float acc = b1[t];
#pragma unroll 8
        for (int l = 0; l < H2; ++l) acc = fmaf(h[l], K1[l * G + t], acc);
        z[t] = acc;
    }
    __syncthreads();
    if (t < UNITS) yc[t] = sigf(z[240 + t]) * sigf(z[t]) * fmaxf(z[160 + t], 0.f);
}

// ---------------------------------------------------------------------------
// Kernel 2 (fused, COMPUTE-FIRST): per block (4 rows):
//   1) stage x, compute lat -> gates -> y0 entirely (all global LOADS consumed)
//   2) only then issue every nt store (body broadcast + s=0 slice)
// => no wave ever executes a load-use s_waitcnt behind its own stores, so
//    store drain overlaps the next round's compute instead of serializing.
// ---------------------------------------------------------------------------
__global__ __launch_bounds__(TPB)
void main_kernel(const float* __restrict__ x,
                 const float* __restrict__ Wl, const float* __restrict__ bl,
                 const float* __restrict__ Kf, const float* __restrict__ bf,
                 const float* __restrict__ Kb, const float* __restrict__ bb,
                 const float* __restrict__ K1, const float* __restrict__ b1,
                 const float* __restrict__ yc,
                 float* __restrict__ out) {
    __shared__ float xs[RPB * IN_DIM];      // 4 KB
    __shared__ float lat_s[RPB * LATENT];   // 2 KB
    __shared__ float h_s[RPB * H2];         // 2.5 KB
    __shared__ f4 yc4s[UNITS / 4];          // 320 B

    const int t = threadIdx.x;
    const int R0 = blockIdx.x * RPB;

    if (t < UNITS / 4) yc4s[t] = ((const f4*)yc)[t];
    // stage x tile (4 rows x 256 = 256 float4)
    {
        const f4* xg = (const f4*)(x + (size_t)R0 * IN_DIM);
        f4* xs4 = (f4*)xs;
        if (t < RPB * IN_DIM / 4) xs4[t] = xg[t];
    }
    __syncthreads();

    const f4 yv = yc4s[t % (UNITS / 4)];    // LDS read, constant per thread

    // ---- lat = x @ W_lat + b_lat : 512 outputs (4 rows x 128 cols) ----
    if (t < 512) {
        const int row = t >> 7, col = t & 127;
        float acc = bl[col];
        const float* xr = xs + row * IN_DIM;
#pragma unroll 8
        for (int l = 0; l < IN_DIM; ++l) acc = fmaf(xr[l], Wl[l * LATENT + col], acc);
        lat_s[row * LATENT + col] = acc;
    }
    __syncthreads();

    // ---- fw gates on t<320, bw gates on t>=320 (f dead: c0=0; relu(c)=c) ----
    {
        const int half = t / G;            // wave-uniform (320 = 5 waves)
        const int tt = t - half * G;       // 0..319
        const int row = tt / UNITS;        // 0..3
        const int u = tt - row * UNITS;    // 0..79
        const float* K   = half ? Kb : Kf;
        const float* bia = half ? bb : bf;
        float ai = 0.f, ac = 0.f, ao = 0.f;
        const float* lr = lat_s + row * LATENT;
#pragma unroll 4
        for (int k = 0; k < LATENT; ++k) {
            const float lv = lr[k];
            ai = fmaf(lv, K[k * G + u], ai);
            ac = fmaf(lv, K[k * G + 160 + u], ac);
            ao = fmaf(lv, K[k * G + 240 + u], ao);
        }
        h_s[row * H2 + half * UNITS + u] =
            sigf(ao + bia[240 + u]) * sigf(ai + bia[u]) * fmaxf(ac + bia[160 + u], 0.f);
    }
    __syncthreads();

    // ---- output LSTM: y0 into registers (last global loads) ----
    float yout = 0.f;
    size_t yoff = 0;
    if (t < G) {
        const int row = t / UNITS;         // 0..3
        const int u = t - row * UNITS;     // 0..79
        float ai = 0.f, ac = 0.f, ao = 0.f;
        const float* hr = h_s + row * H2;
#pragma unroll 4
        for (int k = 0; k < H2; ++k) {
            const float hv = hr[k];
            ai = fmaf(hv, K1[k * G + u], ai);
            ac = fmaf(hv, K1[k * G + 160 + u], ac);
            ao = fmaf(hv, K1[k * G + 240 + u], ao);
        }
        yout = sigf(ao + b1[240 + u]) * sigf(ai + b1[u]) * fmaxf(ac + b1[160 + u], 0.f);
        yoff = (size_t)(R0 + row) * SEQ * UNITS + u;
    }

    // keep every store below every load-use (no vmcnt interlock)
    __builtin_amdgcn_sched_barrier(0);

    // ---- store phase: nothing after this but endpgm ----
    {
        f4* out4 = (f4*)out;
        const int per_row = (SEQ - 1) * UNITS / 4;  // 5100
#pragma unroll
        for (int r = 0; r < RPB; ++r) {
            f4* rowp = out4 + (size_t)(R0 + r) * (SEQ * UNITS / 4) + (UNITS / 4);
#pragma unroll
            for (int k = 0; k < 8; ++k) {
                const int j = t + k * TPB;
                if (j < per_row) __builtin_nontemporal_store(yv, rowp + j);
            }
        }
        if (t < G) __builtin_nontemporal_store(yout, out + yoff);
    }
}

extern "C" void kernel_launch(void* const* d_in, const int* in_sizes, int n_in,
                              void* d_out, int out_size, void* d_ws, size_t ws_size,
                              hipStream_t stream) {
    const float* x   = (const float*)d_in[0];
    // d_in[1] = size (scalar, fixed 256)
    const float* Wl  = (const float*)d_in[2];
    const float* bl  = (const float*)d_in[3];
    const float* Kf  = (const float*)d_in[4];
    const float* bf  = (const float*)d_in[5];
    const float* Kb  = (const float*)d_in[6];
    const float* bb  = (const float*)d_in[7];
    const float* K1  = (const float*)d_in[8];
    const float* b1  = (const float*)d_in[9];
    float* out = (float*)d_out;
    float* yc  = (float*)d_ws;   // 80 floats

    yc_kernel<<<1, 640, 0, stream>>>(Kf, bf, Kb, bb, K1, b1, yc);
    main_kernel<<<NBLK, TPB, 0, stream>>>(x, Wl, bl, Kf, bf, Kb, bb, K1, b1, yc, out);
}